// Round 1
// baseline (399.667 us; speedup 1.0000x reference)
//
#include <hip/hip_runtime.h>

typedef unsigned short u16;
typedef unsigned int u32;
typedef short bf16x8 __attribute__((ext_vector_type(8)));
typedef float f32x4 __attribute__((ext_vector_type(4)));

#define AS_GLOBAL __attribute__((address_space(1)))
#define AS_LDS __attribute__((address_space(3)))

__device__ __forceinline__ void async16(const void* g, void* l) {
  __builtin_amdgcn_global_load_lds((const AS_GLOBAL u32*)g, (AS_LDS u32*)l, 16, 0, 0);
}

__device__ __forceinline__ u16 f2bf(float f) {
  u32 u = __builtin_bit_cast(u32, f);
  u += 0x7FFFu + ((u >> 16) & 1u);   // round-to-nearest-even
  return (u16)(u >> 16);
}

// ---------------- Pass A: f32 -> bf16 convert, x4 vectorized ----------------
__global__ __launch_bounds__(256) void cvt_bf16(const float* __restrict__ src,
                                                u16* __restrict__ dst, int n4) {
  int i = blockIdx.x * blockDim.x + threadIdx.x;
  if (i >= n4) return;
  float4 f = reinterpret_cast<const float4*>(src)[i];
  ushort4 o;
  o.x = f2bf(f.x); o.y = f2bf(f.y); o.z = f2bf(f.z); o.w = f2bf(f.w);
  reinterpret_cast<ushort4*>(dst)[i] = o;
}

// ---------------- Pass B: QKV projection GEMM (C = X * W^T) ----------------
// X: [8192][1024] bf16 row-major; W: [1024][1024] bf16 row-major (out_dim major)
// Out: bf16 scattered to [B=4][H=16][T=2048][hd=64]
__global__ __launch_bounds__(256, 2) void qkv_gemm(const u16* __restrict__ X,
                                                   const u16* __restrict__ W,
                                                   u16* __restrict__ O) {
  const int z = blockIdx.z;
  const u16* Wz = W + (size_t)z * (1024 * 1024);
  u16* Oz = O + (size_t)z * (8192 * 1024);

  __shared__ __align__(16) u16 As[128 * 32];
  __shared__ __align__(16) u16 Bs[128 * 32];

  const int t = threadIdx.x;
  const int lane = t & 63, w = t >> 6, quad = lane >> 4, lq = lane & 15;
  const int wm = (w >> 1) * 64, wn = (w & 1) * 64;
  const size_t m0 = (size_t)blockIdx.y * 128;
  const int n0 = blockIdx.x * 128;
  const int srow = t >> 2, sseg = (t & 3) * 8;

  f32x4 acc[4][4];
#pragma unroll
  for (int i = 0; i < 4; ++i)
#pragma unroll
    for (int j = 0; j < 4; ++j) acc[i][j] = f32x4{0.f, 0.f, 0.f, 0.f};

  const u16* ga = X + (m0 + srow) * 1024 + sseg;
  const u16* gb = Wz + (size_t)(n0 + srow) * 1024 + sseg;

  for (int kt = 0; kt < 32; ++kt) {
    const int k0 = kt * 32;
    __syncthreads();
    async16(ga + k0, &As[srow * 32 + sseg]);
    async16(ga + 64 * 1024 + k0, &As[(64 + srow) * 32 + sseg]);
    async16(gb + k0, &Bs[srow * 32 + sseg]);
    async16(gb + 64 * 1024 + k0, &Bs[(64 + srow) * 32 + sseg]);
    __syncthreads();
    bf16x8 af[4], bfr[4];
#pragma unroll
    for (int i = 0; i < 4; ++i)
      af[i] = *reinterpret_cast<const bf16x8*>(&As[(wm + i * 16 + lq) * 32 + quad * 8]);
#pragma unroll
    for (int j = 0; j < 4; ++j)
      bfr[j] = *reinterpret_cast<const bf16x8*>(&Bs[(wn + j * 16 + lq) * 32 + quad * 8]);
#pragma unroll
    for (int i = 0; i < 4; ++i)
#pragma unroll
      for (int j = 0; j < 4; ++j)
        acc[i][j] = __builtin_amdgcn_mfma_f32_16x16x32_bf16(af[i], bfr[j], acc[i][j], 0, 0, 0);
  }

  // epilogue: C row m -> (b, t), col n -> (h, d); dst [b][h][t][d] bf16
#pragma unroll
  for (int i = 0; i < 4; ++i) {
#pragma unroll
    for (int j = 0; j < 4; ++j) {
      const int n = n0 + wn + j * 16 + lq;
      const int hh = n >> 6, d = n & 63;
#pragma unroll
      for (int r = 0; r < 4; ++r) {
        const size_t m = m0 + wm + i * 16 + quad * 4 + r;
        const size_t bb = m >> 11, tt = m & 2047;
        Oz[((bb * 16 + hh) * 2048 + tt) * 64 + d] = f2bf(acc[i][j][r]);
      }
    }
  }
}

// ---------------- Pass C: flash attention with palace mask ----------------
// Q,K,V: bf16 [B][H][T][64]; out: f32 [B][T][1024]
// Block = 4 waves; wave w owns q-rows [qt*64 + w*16, +16); loops 64-key tiles.
__global__ __launch_bounds__(256, 2) void palace_attn(const u16* __restrict__ Q,
                                                      const u16* __restrict__ K,
                                                      const u16* __restrict__ V,
                                                      float* __restrict__ out,
                                                      const float* __restrict__ wptr) {
  const int qt = blockIdx.x, h = blockIdx.y, b = blockIdx.z;
  const size_t base = ((size_t)(b * 16 + h)) * (2048 * 64);

  // stride 72 elements = 144 B = 9*16 B: keeps b128 reads 16B-aligned, staggers banks
  __shared__ __align__(16) u16 Ks[64 * 72];
  __shared__ __align__(16) u16 Vt[64 * 72];
  __shared__ __align__(16) u16 Ps[4][16 * 72];

  const int t = threadIdx.x;
  const int w = t >> 6, lane = t & 63, quad = lane >> 4, lq = lane & 15;
  const float sig = 1.f / (1.f + __expf(-wptr[0]));
  const float sig8 = 0.125f * sig;

  // Q A-fragments: A[m=lq][k=quad*8+j], k-chunks 0-31 / 32-63
  const size_t qrow = (size_t)(qt * 64 + w * 16 + lq);
  const bf16x8 qa0 = *reinterpret_cast<const bf16x8*>(Q + base + qrow * 64 + quad * 8);
  const bf16x8 qa1 = *reinterpret_cast<const bf16x8*>(Q + base + qrow * 64 + 32 + quad * 8);

  f32x4 o[4];
  float mrow[4], lrow[4];
#pragma unroll
  for (int r = 0; r < 4; ++r) {
    o[r] = f32x4{0.f, 0.f, 0.f, 0.f};
    mrow[r] = -1e30f;
    lrow[r] = 0.f;
  }

  const int skey = t >> 2, sdg = (t & 3) * 16;  // K staging
  const int vkey = lane, vdg = w * 16;          // V transpose staging
  const int qmod = w * 16 + quad * 4;           // q-row (mod 64) base for this lane

  for (int kt = 0; kt < 32; ++kt) {
    const u16* kg = K + base + (size_t)kt * 4096;
    const u16* vg = V + base + (size_t)kt * 4096;
    __syncthreads();
    {  // K tile [key][d]
      uint4 a = *reinterpret_cast<const uint4*>(kg + skey * 64 + sdg);
      uint4 c = *reinterpret_cast<const uint4*>(kg + skey * 64 + sdg + 8);
      *reinterpret_cast<uint4*>(&Ks[skey * 72 + sdg]) = a;
      *reinterpret_cast<uint4*>(&Ks[skey * 72 + sdg + 8]) = c;
    }
    {  // V tile transposed [d][key]
      u16 tmp[16];
      *reinterpret_cast<uint4*>(tmp) = *reinterpret_cast<const uint4*>(vg + vkey * 64 + vdg);
      *reinterpret_cast<uint4*>(tmp + 8) = *reinterpret_cast<const uint4*>(vg + vkey * 64 + vdg + 8);
#pragma unroll
      for (int e = 0; e < 16; ++e) Vt[(vdg + e) * 72 + vkey] = tmp[e];
    }
    __syncthreads();

    // S = Q K^T : 4 col-groups of 16 keys
    f32x4 s[4];
#pragma unroll
    for (int c = 0; c < 4; ++c) {
      bf16x8 kb0 = *reinterpret_cast<const bf16x8*>(&Ks[(c * 16 + lq) * 72 + quad * 8]);
      bf16x8 kb1 = *reinterpret_cast<const bf16x8*>(&Ks[(c * 16 + lq) * 72 + 32 + quad * 8]);
      f32x4 zz = {0.f, 0.f, 0.f, 0.f};
      zz = __builtin_amdgcn_mfma_f32_16x16x32_bf16(qa0, kb0, zz, 0, 0, 0);
      s[c] = __builtin_amdgcn_mfma_f32_16x16x32_bf16(qa1, kb1, zz, 0, 0, 0);
    }

    // multiplicative palace mask on logits + scale; tile row-max
    float tmax[4] = {-1e30f, -1e30f, -1e30f, -1e30f};
#pragma unroll
    for (int c = 0; c < 4; ++c) {
      const int kk = (c * 16 + lq) >> 3;  // key palace id (key mod 64 == c*16+lq)
#pragma unroll
      for (int r = 0; r < 4; ++r) {
        const float f = s[c][r] * ((((qmod + r) >> 3) == kk) ? 0.125f : sig8);
        s[c][r] = f;
        tmax[r] = fmaxf(tmax[r], f);
      }
    }
#pragma unroll
    for (int off = 8; off; off >>= 1)
#pragma unroll
      for (int r = 0; r < 4; ++r) tmax[r] = fmaxf(tmax[r], __shfl_xor(tmax[r], off, 64));

    float alpha[4], tsum[4] = {0.f, 0.f, 0.f, 0.f};
#pragma unroll
    for (int r = 0; r < 4; ++r) {
      const float nm = fmaxf(mrow[r], tmax[r]);
      alpha[r] = __expf(mrow[r] - nm);
      mrow[r] = nm;
    }
#pragma unroll
    for (int c = 0; c < 4; ++c)
#pragma unroll
      for (int r = 0; r < 4; ++r) {
        const float p = __expf(s[c][r] - mrow[r]);
        s[c][r] = p;
        tsum[r] += p;
      }
#pragma unroll
    for (int off = 8; off; off >>= 1)
#pragma unroll
      for (int r = 0; r < 4; ++r) tsum[r] += __shfl_xor(tsum[r], off, 64);
#pragma unroll
    for (int r = 0; r < 4; ++r) lrow[r] = lrow[r] * alpha[r] + tsum[r];
#pragma unroll
    for (int c = 0; c < 4; ++c)
#pragma unroll
      for (int r = 0; r < 4; ++r) o[c][r] *= alpha[r];

    // P: C-layout -> LDS -> A-layout (per-wave scratch)
#pragma unroll
    for (int c = 0; c < 4; ++c)
#pragma unroll
      for (int r = 0; r < 4; ++r)
        Ps[w][(quad * 4 + r) * 72 + c * 16 + lq] = f2bf(s[c][r]);
    __syncthreads();

    const bf16x8 pa0 = *reinterpret_cast<const bf16x8*>(&Ps[w][lq * 72 + quad * 8]);
    const bf16x8 pa1 = *reinterpret_cast<const bf16x8*>(&Ps[w][lq * 72 + 32 + quad * 8]);
#pragma unroll
    for (int c = 0; c < 4; ++c) {
      bf16x8 vb0 = *reinterpret_cast<const bf16x8*>(&Vt[(c * 16 + lq) * 72 + quad * 8]);
      bf16x8 vb1 = *reinterpret_cast<const bf16x8*>(&Vt[(c * 16 + lq) * 72 + 32 + quad * 8]);
      o[c] = __builtin_amdgcn_mfma_f32_16x16x32_bf16(pa0, vb0, o[c], 0, 0, 0);
      o[c] = __builtin_amdgcn_mfma_f32_16x16x32_bf16(pa1, vb1, o[c], 0, 0, 0);
    }
  }

  // epilogue: out[b][t][h*64 + d] f32
#pragma unroll
  for (int r = 0; r < 4; ++r) {
    const float inv = 1.f / lrow[r];
    const size_t trow = (size_t)(qt * 64 + w * 16 + quad * 4 + r);
    float* op = out + ((size_t)b * 2048 + trow) * 1024 + h * 64 + lq;
#pragma unroll
    for (int c = 0; c < 4; ++c) op[c * 16] = o[c][r] * inv;
  }
}

extern "C" void kernel_launch(void* const* d_in, const int* in_sizes, int n_in,
                              void* d_out, int out_size, void* d_ws, size_t ws_size,
                              hipStream_t stream) {
  (void)in_sizes; (void)n_in; (void)out_size; (void)ws_size;
  const float* x = (const float*)d_in[0];
  const float* Wq = (const float*)d_in[1];
  const float* Wk = (const float*)d_in[2];
  const float* Wv = (const float*)d_in[3];
  const float* wip = (const float*)d_in[4];
  float* out = (float*)d_out;

  // workspace layout (elements of u16):
  // xb: 8388608 | wb: 3*1048576 | qb,kb,vb: 3*8388608  => ~70 MB total
  u16* xb = (u16*)d_ws;
  u16* wb = xb + 8388608;
  u16* qb = wb + 3145728;
  u16* kb = qb + 8388608;
  u16* vb = kb + 8388608;

  cvt_bf16<<<8192, 256, 0, stream>>>(x, xb, 2097152);
  cvt_bf16<<<1024, 256, 0, stream>>>(Wq, wb, 262144);
  cvt_bf16<<<1024, 256, 0, stream>>>(Wk, wb + 1048576, 262144);
  cvt_bf16<<<1024, 256, 0, stream>>>(Wv, wb + 2097152, 262144);
  qkv_gemm<<<dim3(8, 64, 3), 256, 0, stream>>>(xb, wb, qb);
  palace_attn<<<dim3(32, 16, 4), 256, 0, stream>>>(qb, kb, vb, out, wip);
}

// Round 2
// 272.562 us; speedup vs baseline: 1.4663x; 1.4663x over previous
//
#include <hip/hip_runtime.h>

typedef unsigned short u16;
typedef unsigned int u32;
typedef short bf16x8 __attribute__((ext_vector_type(8)));
typedef float f32x4 __attribute__((ext_vector_type(4)));

#define AS_GLOBAL __attribute__((address_space(1)))
#define AS_LDS __attribute__((address_space(3)))

__device__ __forceinline__ void async16(const void* g, void* l) {
  __builtin_amdgcn_global_load_lds((const AS_GLOBAL u32*)g, (AS_LDS u32*)l, 16, 0, 0);
}

__device__ __forceinline__ u16 f2bf(float f) {
  u32 u = __builtin_bit_cast(u32, f);
  u += 0x7FFFu + ((u >> 16) & 1u);   // RNE
  return (u16)(u >> 16);
}

// pack two f32 -> two bf16 (truncation; bias cancels under softmax normalization)
__device__ __forceinline__ u32 pk2bf(float lo, float hi) {
  return __builtin_amdgcn_perm(__builtin_bit_cast(u32, hi),
                               __builtin_bit_cast(u32, lo), 0x07060302u);
}

__device__ __forceinline__ float fexp2(float x) {
#if __has_builtin(__builtin_amdgcn_exp2f)
  return __builtin_amdgcn_exp2f(x);
#else
  return exp2f(x);
#endif
}

// ---------------- Pass A: f32 -> bf16 convert ----------------
__global__ __launch_bounds__(256) void cvt_bf16(const float* __restrict__ src,
                                                u16* __restrict__ dst, int n4) {
  int i = blockIdx.x * blockDim.x + threadIdx.x;
  if (i >= n4) return;
  float4 f = reinterpret_cast<const float4*>(src)[i];
  ushort4 o;
  o.x = f2bf(f.x); o.y = f2bf(f.y); o.z = f2bf(f.z); o.w = f2bf(f.w);
  reinterpret_cast<ushort4*>(dst)[i] = o;
}

// ---------------- Pass B: QKV projection GEMM (C = X * W^T) ----------------
// z=0 (Q), z=1 (K): out [B][H][T][64]; z=2 (V): out TRANSPOSED [B][H][64][T]
__global__ __launch_bounds__(256, 2) void qkv_gemm(const u16* __restrict__ X,
                                                   const u16* __restrict__ W,
                                                   u16* __restrict__ O) {
  const int z = blockIdx.z;
  const u16* Wz = W + (size_t)z * (1024 * 1024);
  u16* Oz = O + (size_t)z * (8192 * 1024);

  __shared__ __align__(16) u16 As[128 * 32];
  __shared__ __align__(16) u16 Bs[128 * 32];

  const int t = threadIdx.x;
  const int lane = t & 63, w = t >> 6, quad = lane >> 4, lq = lane & 15;
  const int wm = (w >> 1) * 64, wn = (w & 1) * 64;
  const size_t m0 = (size_t)blockIdx.y * 128;
  const int n0 = blockIdx.x * 128;
  const int srow = t >> 2, sseg = (t & 3) * 8;

  f32x4 acc[4][4];
#pragma unroll
  for (int i = 0; i < 4; ++i)
#pragma unroll
    for (int j = 0; j < 4; ++j) acc[i][j] = f32x4{0.f, 0.f, 0.f, 0.f};

  const u16* ga = X + (m0 + srow) * 1024 + sseg;
  const u16* gb = Wz + (size_t)(n0 + srow) * 1024 + sseg;

  for (int kt = 0; kt < 32; ++kt) {
    const int k0 = kt * 32;
    __syncthreads();
    async16(ga + k0, &As[srow * 32 + sseg]);
    async16(ga + 64 * 1024 + k0, &As[(64 + srow) * 32 + sseg]);
    async16(gb + k0, &Bs[srow * 32 + sseg]);
    async16(gb + 64 * 1024 + k0, &Bs[(64 + srow) * 32 + sseg]);
    __syncthreads();
    bf16x8 af[4], bfr[4];
#pragma unroll
    for (int i = 0; i < 4; ++i)
      af[i] = *reinterpret_cast<const bf16x8*>(&As[(wm + i * 16 + lq) * 32 + quad * 8]);
#pragma unroll
    for (int j = 0; j < 4; ++j)
      bfr[j] = *reinterpret_cast<const bf16x8*>(&Bs[(wn + j * 16 + lq) * 32 + quad * 8]);
#pragma unroll
    for (int i = 0; i < 4; ++i)
#pragma unroll
      for (int j = 0; j < 4; ++j)
        acc[i][j] = __builtin_amdgcn_mfma_f32_16x16x32_bf16(af[i], bfr[j], acc[i][j], 0, 0, 0);
  }

#pragma unroll
  for (int i = 0; i < 4; ++i) {
#pragma unroll
    for (int j = 0; j < 4; ++j) {
      const int n = n0 + wn + j * 16 + lq;
      const int hh = n >> 6, d = n & 63;
#pragma unroll
      for (int r = 0; r < 4; ++r) {
        const size_t m = m0 + wm + i * 16 + quad * 4 + r;
        const size_t bb = m >> 11, tt = m & 2047;
        if (z != 2)
          Oz[((bb * 16 + hh) * 2048 + tt) * 64 + d] = f2bf(acc[i][j][r]);
        else
          Oz[((bb * 16 + hh) * 64 + d) * 2048 + tt] = f2bf(acc[i][j][r]);
      }
    }
  }
}

// ---------------- Pass C: flash attention, S^T-form, fixed-max softmax ----------------
// Q,K: bf16 [B][H][2048][64]; Vt: bf16 [B][H][64][2048]; out f32 [B][2048][1024]
// Block = 4 waves; wave owns 32 q-rows (2 qgroups of 16). 64-key tiles.
__global__ __launch_bounds__(256, 4) void palace_attn(const u16* __restrict__ Q,
                                                      const u16* __restrict__ K,
                                                      const u16* __restrict__ Vt,
                                                      float* __restrict__ out,
                                                      const float* __restrict__ wptr) {
  const int qt = blockIdx.x, h = blockIdx.y, b = blockIdx.z;
  const size_t base = (size_t)(b * 16 + h) * (2048 * 64);

  __shared__ __align__(16) u16 Ks[64 * 64];       // [key][d], XOR-swizzled 16B chunks
  __shared__ __align__(16) u16 Vs[64 * 64];       // [d][key], XOR-swizzled 16B chunks
  __shared__ __align__(16) u16 Ps[4][32 * 72];    // per-wave P scratch [q][key], pad 72

  const int t = threadIdx.x;
  const int w = t >> 6, lane = t & 63, quad = lane >> 4, lq = lane & 15;
  const float sig = 1.f / (1.f + __expf(-wptr[0]));
  const float Ci = 0.125f * 1.44269504f;   // intra coeff (scale * log2 e)
  const float Co = Ci * sig;               // inter coeff
  const float MC = 14.4269504f;            // fixed softmax offset: 10 * log2 e

  // palace-mask coefficients, hoisted out of the K-loop.
  // element (key = kg*16+quad*4+r, q = qg*16+lq): palace_k = kg*2 + (quad>>1) (r<4 can't cross)
  float coef[2][4];
#pragma unroll
  for (int qg = 0; qg < 2; ++qg) {
    const int qp = (((w & 1) * 32) + qg * 16 + lq) >> 3;
#pragma unroll
    for (int kg = 0; kg < 4; ++kg)
      coef[qg][kg] = (qp == kg * 2 + (quad >> 1)) ? Ci : Co;
  }

  // Q B-frags in registers: B[k=d][n=q], lane n=lq -> q=qg*16+lq, d = kc*32+quad*8+j
  bf16x8 qf[2][2];
#pragma unroll
  for (int qg = 0; qg < 2; ++qg)
#pragma unroll
    for (int kc = 0; kc < 2; ++kc)
      qf[qg][kc] = *reinterpret_cast<const bf16x8*>(
          Q + base + (size_t)(qt * 128 + w * 32 + qg * 16 + lq) * 64 + kc * 32 + quad * 8);

  // staging offsets: slot = r*256+t; row = slot>>3; logical chunk = (slot&7) ^ (row&7)
  int ko[2], vo[2];
#pragma unroll
  for (int r = 0; r < 2; ++r) {
    const int slot = r * 256 + t;
    const int row = slot >> 3;
    const int cl = (slot & 7) ^ (row & 7);
    ko[r] = row * 64 + cl * 8;     // K: [key][64]
    vo[r] = row * 2048 + cl * 8;   // Vt: [d][2048]
  }

  f32x4 O[2][4];
  float lsum[2] = {0.f, 0.f};
#pragma unroll
  for (int qg = 0; qg < 2; ++qg)
#pragma unroll
    for (int dg = 0; dg < 4; ++dg) O[qg][dg] = f32x4{0.f, 0.f, 0.f, 0.f};

  const int x7 = lq & 7;

  for (int kt = 0; kt < 32; ++kt) {
    const u16* kgp = K + base + (size_t)kt * 4096;
    const u16* vgp = Vt + base + (size_t)kt * 64;
    __syncthreads();   // all reads of previous tile done
    async16(kgp + ko[0], &Ks[(w * 64) * 8]);
    async16(kgp + ko[1], &Ks[(256 + w * 64) * 8]);
    async16(vgp + vo[0], &Vs[(w * 64) * 8]);
    async16(vgp + vo[1], &Vs[(256 + w * 64) * 8]);
    __syncthreads();   // DMA complete

    // S^T[key][q] = K · Q^T : A = K-frag (m=key), B = Q-frag (n=q)
    f32x4 s[4][2];
#pragma unroll
    for (int kg = 0; kg < 4; ++kg) {
      const bf16x8 kf0 = *reinterpret_cast<const bf16x8*>(
          &Ks[(((kg * 16 + lq) * 8) + (quad ^ x7)) * 8]);
      const bf16x8 kf1 = *reinterpret_cast<const bf16x8*>(
          &Ks[(((kg * 16 + lq) * 8) + ((4 + quad) ^ x7)) * 8]);
#pragma unroll
      for (int qg = 0; qg < 2; ++qg) {
        f32x4 z = {0.f, 0.f, 0.f, 0.f};
        z = __builtin_amdgcn_mfma_f32_16x16x32_bf16(kf0, qf[qg][0], z, 0, 0, 0);
        s[kg][qg] = __builtin_amdgcn_mfma_f32_16x16x32_bf16(kf1, qf[qg][1], z, 0, 0, 0);
      }
    }

    // softmax (fixed max): p = exp2(s*coef - MC); accumulate per-lane row sums
#pragma unroll
    for (int qg = 0; qg < 2; ++qg)
#pragma unroll
      for (int kg = 0; kg < 4; ++kg) {
        float p0 = fexp2(__builtin_fmaf(s[kg][qg][0], coef[qg][kg], -MC));
        float p1 = fexp2(__builtin_fmaf(s[kg][qg][1], coef[qg][kg], -MC));
        float p2 = fexp2(__builtin_fmaf(s[kg][qg][2], coef[qg][kg], -MC));
        float p3 = fexp2(__builtin_fmaf(s[kg][qg][3], coef[qg][kg], -MC));
        lsum[qg] += (p0 + p1) + (p2 + p3);
        uint2 pk;
        pk.x = pk2bf(p0, p1);
        pk.y = pk2bf(p2, p3);
        *reinterpret_cast<uint2*>(&Ps[w][(qg * 16 + lq) * 72 + kg * 16 + quad * 4]) = pk;
      }
    // per-wave scratch: order write->read within the wave, no block barrier needed
    __asm__ volatile("s_waitcnt lgkmcnt(0)" ::: "memory");

    bf16x8 pf[2][2];
#pragma unroll
    for (int qg = 0; qg < 2; ++qg)
#pragma unroll
      for (int kc = 0; kc < 2; ++kc)
        pf[qg][kc] = *reinterpret_cast<const bf16x8*>(
            &Ps[w][(qg * 16 + lq) * 72 + kc * 32 + quad * 8]);

    // O[q][d] += P · V : A = P-frag (m=q), B = Vt-frag (n=d)
#pragma unroll
    for (int dg = 0; dg < 4; ++dg) {
      const bf16x8 vf0 = *reinterpret_cast<const bf16x8*>(
          &Vs[(((dg * 16 + lq) * 8) + (quad ^ x7)) * 8]);
      const bf16x8 vf1 = *reinterpret_cast<const bf16x8*>(
          &Vs[(((dg * 16 + lq) * 8) + ((4 + quad) ^ x7)) * 8]);
#pragma unroll
      for (int qg = 0; qg < 2; ++qg) {
        O[qg][dg] = __builtin_amdgcn_mfma_f32_16x16x32_bf16(pf[qg][0], vf0, O[qg][dg], 0, 0, 0);
        O[qg][dg] = __builtin_amdgcn_mfma_f32_16x16x32_bf16(pf[qg][1], vf1, O[qg][dg], 0, 0, 0);
      }
    }
  }

  // finalize l (reduce over quad: lanes lane^16, lane^32 hold the other key-subsets)
  float inv[2];
#pragma unroll
  for (int qg = 0; qg < 2; ++qg) {
    float l = lsum[qg];
    l += __shfl_xor(l, 16, 64);
    l += __shfl_xor(l, 32, 64);
    inv[qg] = 1.f / l;
  }

  // epilogue: O[qg][dg][r] -> out[b][t = qbase+qg*16+quad*4+r][h*64 + dg*16 + lq]
#pragma unroll
  for (int qg = 0; qg < 2; ++qg) {
#pragma unroll
    for (int r = 0; r < 4; ++r) {
      const float iv = __shfl(inv[qg], quad * 4 + r, 64);
      const size_t trow = (size_t)(qt * 128 + w * 32 + qg * 16 + quad * 4 + r);
      float* op = out + ((size_t)b * 2048 + trow) * 1024 + h * 64 + lq;
#pragma unroll
      for (int dg = 0; dg < 4; ++dg) op[dg * 16] = O[qg][dg][r] * iv;
    }
  }
}

extern "C" void kernel_launch(void* const* d_in, const int* in_sizes, int n_in,
                              void* d_out, int out_size, void* d_ws, size_t ws_size,
                              hipStream_t stream) {
  (void)in_sizes; (void)n_in; (void)out_size; (void)ws_size;
  const float* x = (const float*)d_in[0];
  const float* Wq = (const float*)d_in[1];
  const float* Wk = (const float*)d_in[2];
  const float* Wv = (const float*)d_in[3];
  const float* wip = (const float*)d_in[4];
  float* out = (float*)d_out;

  u16* xb = (u16*)d_ws;
  u16* wb = xb + 8388608;
  u16* qb = wb + 3145728;
  u16* kb = qb + 8388608;
  u16* vb = kb + 8388608;   // holds V^T [B][H][64][2048]

  cvt_bf16<<<8192, 256, 0, stream>>>(x, xb, 2097152);
  cvt_bf16<<<1024, 256, 0, stream>>>(Wq, wb, 262144);
  cvt_bf16<<<1024, 256, 0, stream>>>(Wk, wb + 1048576, 262144);
  cvt_bf16<<<1024, 256, 0, stream>>>(Wv, wb + 2097152, 262144);
  qkv_gemm<<<dim3(8, 64, 3), 256, 0, stream>>>(xb, wb, qb);
  palace_attn<<<dim3(16, 16, 4), 256, 0, stream>>>(qb, kb, vb, out, wip);
}

// Round 3
// 260.915 us; speedup vs baseline: 1.5318x; 1.0446x over previous
//
#include <hip/hip_runtime.h>

typedef unsigned short u16;
typedef unsigned int u32;
typedef short bf16x8 __attribute__((ext_vector_type(8)));
typedef float f32x4 __attribute__((ext_vector_type(4)));

#define AS_GLOBAL __attribute__((address_space(1)))
#define AS_LDS __attribute__((address_space(3)))

__device__ __forceinline__ void async16(const void* g, void* l) {
  __builtin_amdgcn_global_load_lds((const AS_GLOBAL u32*)g, (AS_LDS u32*)l, 16, 0, 0);
}

__device__ __forceinline__ u16 f2bf(float f) {
  u32 u = __builtin_bit_cast(u32, f);
  u += 0x7FFFu + ((u >> 16) & 1u);   // RNE
  return (u16)(u >> 16);
}

__device__ __forceinline__ u32 pk2bf(float lo, float hi) {
  return __builtin_amdgcn_perm(__builtin_bit_cast(u32, hi),
                               __builtin_bit_cast(u32, lo), 0x07060302u);
}

__device__ __forceinline__ float fexp2(float x) {
#if __has_builtin(__builtin_amdgcn_exp2f)
  return __builtin_amdgcn_exp2f(x);
#else
  return exp2f(x);
#endif
}

// ---------------- Pass A: all four f32 -> bf16 converts in one launch ----------------
// blocks [0,8192): x (2097152 float4) | [8192,9216): Wq | [9216,10240): Wk | [10240,11264): Wv
__global__ __launch_bounds__(256) void cvt_all(const float* __restrict__ x,
                                               const float* __restrict__ wq,
                                               const float* __restrict__ wk,
                                               const float* __restrict__ wv,
                                               u16* __restrict__ xb,
                                               u16* __restrict__ wb) {
  const int blk = blockIdx.x;
  const float* src;
  u16* dst;
  int i;
  if (blk < 8192) {
    src = x; dst = xb; i = blk * 256 + threadIdx.x;
  } else if (blk < 9216) {
    src = wq; dst = wb; i = (blk - 8192) * 256 + threadIdx.x;
  } else if (blk < 10240) {
    src = wk; dst = wb + 1048576; i = (blk - 9216) * 256 + threadIdx.x;
  } else {
    src = wv; dst = wb + 2097152; i = (blk - 10240) * 256 + threadIdx.x;
  }
  float4 f = reinterpret_cast<const float4*>(src)[i];
  ushort4 o;
  o.x = f2bf(f.x); o.y = f2bf(f.y); o.z = f2bf(f.z); o.w = f2bf(f.w);
  reinterpret_cast<ushort4*>(dst)[i] = o;
}

// ---------------- Pass B: QKV projection GEMM (C = X * W^T), double-buffered ----------------
// grid: x = m-tile (64), y = n-tile (8), z = matrix (3)
// z=0 (Q), z=1 (K): out [B][H][T][64]; z=2 (V): out TRANSPOSED [B][H][64][T]
__global__ __launch_bounds__(256, 3) void qkv_gemm(const u16* __restrict__ X,
                                                   const u16* __restrict__ W,
                                                   u16* __restrict__ O) {
  const int z = blockIdx.z;
  const u16* Wz = W + (size_t)z * (1024 * 1024);
  u16* Oz = O + (size_t)z * (8192 * 1024);

  __shared__ __align__(16) u16 As[2][128 * 32];
  __shared__ __align__(16) u16 Bs[2][128 * 32];

  const int t = threadIdx.x;
  const int lane = t & 63, w = t >> 6, quad = lane >> 4, lq = lane & 15;
  const int wm = (w >> 1) * 64, wn = (w & 1) * 64;
  const size_t m0 = (size_t)blockIdx.x * 128;
  const int n0 = blockIdx.y * 128;
  const int srow = t >> 2, sseg = (t & 3) * 8;

  f32x4 acc[4][4];
#pragma unroll
  for (int i = 0; i < 4; ++i)
#pragma unroll
    for (int j = 0; j < 4; ++j) acc[i][j] = f32x4{0.f, 0.f, 0.f, 0.f};

  const u16* ga = X + (m0 + srow) * 1024 + sseg;
  const u16* gb = Wz + (size_t)(n0 + srow) * 1024 + sseg;

  // prologue: stage tile 0 into buffer 0
  async16(ga, &As[0][srow * 32 + sseg]);
  async16(ga + 64 * 1024, &As[0][(64 + srow) * 32 + sseg]);
  async16(gb, &Bs[0][srow * 32 + sseg]);
  async16(gb + 64 * 1024, &Bs[0][(64 + srow) * 32 + sseg]);

  for (int kt = 0; kt < 32; ++kt) {
    const int cur = kt & 1;
    __syncthreads();  // drains DMA into buf[cur]; prior reads of buf[cur^1] are done
    if (kt < 31) {
      const int k1 = (kt + 1) * 32;
      async16(ga + k1, &As[cur ^ 1][srow * 32 + sseg]);
      async16(ga + 64 * 1024 + k1, &As[cur ^ 1][(64 + srow) * 32 + sseg]);
      async16(gb + k1, &Bs[cur ^ 1][srow * 32 + sseg]);
      async16(gb + 64 * 1024 + k1, &Bs[cur ^ 1][(64 + srow) * 32 + sseg]);
    }
    bf16x8 af[4], bfr[4];
#pragma unroll
    for (int i = 0; i < 4; ++i)
      af[i] = *reinterpret_cast<const bf16x8*>(&As[cur][(wm + i * 16 + lq) * 32 + quad * 8]);
#pragma unroll
    for (int j = 0; j < 4; ++j)
      bfr[j] = *reinterpret_cast<const bf16x8*>(&Bs[cur][(wn + j * 16 + lq) * 32 + quad * 8]);
#pragma unroll
    for (int i = 0; i < 4; ++i)
#pragma unroll
      for (int j = 0; j < 4; ++j)
        acc[i][j] = __builtin_amdgcn_mfma_f32_16x16x32_bf16(af[i], bfr[j], acc[i][j], 0, 0, 0);
  }

#pragma unroll
  for (int i = 0; i < 4; ++i) {
#pragma unroll
    for (int j = 0; j < 4; ++j) {
      const int n = n0 + wn + j * 16 + lq;
      const int hh = n >> 6, d = n & 63;
#pragma unroll
      for (int r = 0; r < 4; ++r) {
        const size_t m = m0 + wm + i * 16 + quad * 4 + r;
        const size_t bb = m >> 11, tt = m & 2047;
        if (z != 2)
          Oz[((bb * 16 + hh) * 2048 + tt) * 64 + d] = f2bf(acc[i][j][r]);
        else
          Oz[((bb * 16 + hh) * 64 + d) * 2048 + tt] = f2bf(acc[i][j][r]);
      }
    }
  }
}

// ---------------- Pass C: flash attention, S^T-form, fixed-max softmax ----------------
// grid: x = b*16+h (64)  [keeps all q-tiles of a head on one XCD], y = q-tile (16)
// Q,K: bf16 [B][H][2048][64]; Vt: bf16 [B][H][64][2048]; out f32 [B][2048][1024]
__global__ __launch_bounds__(256, 4) void palace_attn(const u16* __restrict__ Q,
                                                      const u16* __restrict__ K,
                                                      const u16* __restrict__ Vt,
                                                      float* __restrict__ out,
                                                      const float* __restrict__ wptr) {
  const int bh = blockIdx.x, qt = blockIdx.y;
  const int h = bh & 15, b = bh >> 4;
  const size_t base = (size_t)bh * (2048 * 64);

  __shared__ __align__(16) u16 Ks[64 * 64];       // [key][d], XOR-swizzled 16B chunks
  __shared__ __align__(16) u16 Vs[64 * 64];       // [d][key], XOR-swizzled 16B chunks
  __shared__ __align__(16) u16 Ps[4][32 * 72];    // per-wave P scratch [q][key], pad 72

  const int t = threadIdx.x;
  const int w = t >> 6, lane = t & 63, quad = lane >> 4, lq = lane & 15;
  const float sig = 1.f / (1.f + __expf(-wptr[0]));
  const float Ci = 0.125f * 1.44269504f;   // intra coeff (scale * log2 e)
  const float Co = Ci * sig;               // inter coeff
  const float MC = 14.4269504f;            // fixed softmax offset: 10 * log2 e

  float coef[2][4];
#pragma unroll
  for (int qg = 0; qg < 2; ++qg) {
    const int qp = (((w & 1) * 32) + qg * 16 + lq) >> 3;
#pragma unroll
    for (int kg = 0; kg < 4; ++kg)
      coef[qg][kg] = (qp == kg * 2 + (quad >> 1)) ? Ci : Co;
  }

  bf16x8 qf[2][2];
#pragma unroll
  for (int qg = 0; qg < 2; ++qg)
#pragma unroll
    for (int kc = 0; kc < 2; ++kc)
      qf[qg][kc] = *reinterpret_cast<const bf16x8*>(
          Q + base + (size_t)(qt * 128 + w * 32 + qg * 16 + lq) * 64 + kc * 32 + quad * 8);

  int ko[2], vo[2];
#pragma unroll
  for (int r = 0; r < 2; ++r) {
    const int slot = r * 256 + t;
    const int row = slot >> 3;
    const int cl = (slot & 7) ^ (row & 7);
    ko[r] = row * 64 + cl * 8;     // K: [key][64]
    vo[r] = row * 2048 + cl * 8;   // Vt: [d][2048]
  }

  f32x4 O[2][4];
  float lsum[2] = {0.f, 0.f};
#pragma unroll
  for (int qg = 0; qg < 2; ++qg)
#pragma unroll
    for (int dg = 0; dg < 4; ++dg) O[qg][dg] = f32x4{0.f, 0.f, 0.f, 0.f};

  const int x7 = lq & 7;

  for (int kt = 0; kt < 32; ++kt) {
    const u16* kgp = K + base + (size_t)kt * 4096;
    const u16* vgp = Vt + base + (size_t)kt * 64;
    __syncthreads();
    async16(kgp + ko[0], &Ks[(w * 64) * 8]);
    async16(kgp + ko[1], &Ks[(256 + w * 64) * 8]);
    async16(vgp + vo[0], &Vs[(w * 64) * 8]);
    async16(vgp + vo[1], &Vs[(256 + w * 64) * 8]);
    __syncthreads();

    // S^T[key][q] = K · Q^T
    f32x4 s[4][2];
#pragma unroll
    for (int kg = 0; kg < 4; ++kg) {
      const bf16x8 kf0 = *reinterpret_cast<const bf16x8*>(
          &Ks[(((kg * 16 + lq) * 8) + (quad ^ x7)) * 8]);
      const bf16x8 kf1 = *reinterpret_cast<const bf16x8*>(
          &Ks[(((kg * 16 + lq) * 8) + ((4 + quad) ^ x7)) * 8]);
#pragma unroll
      for (int qg = 0; qg < 2; ++qg) {
        f32x4 z = {0.f, 0.f, 0.f, 0.f};
        z = __builtin_amdgcn_mfma_f32_16x16x32_bf16(kf0, qf[qg][0], z, 0, 0, 0);
        s[kg][qg] = __builtin_amdgcn_mfma_f32_16x16x32_bf16(kf1, qf[qg][1], z, 0, 0, 0);
      }
    }

#pragma unroll
    for (int qg = 0; qg < 2; ++qg)
#pragma unroll
      for (int kg = 0; kg < 4; ++kg) {
        float p0 = fexp2(__builtin_fmaf(s[kg][qg][0], coef[qg][kg], -MC));
        float p1 = fexp2(__builtin_fmaf(s[kg][qg][1], coef[qg][kg], -MC));
        float p2 = fexp2(__builtin_fmaf(s[kg][qg][2], coef[qg][kg], -MC));
        float p3 = fexp2(__builtin_fmaf(s[kg][qg][3], coef[qg][kg], -MC));
        lsum[qg] += (p0 + p1) + (p2 + p3);
        uint2 pk;
        pk.x = pk2bf(p0, p1);
        pk.y = pk2bf(p2, p3);
        *reinterpret_cast<uint2*>(&Ps[w][(qg * 16 + lq) * 72 + kg * 16 + quad * 4]) = pk;
      }
    __asm__ volatile("s_waitcnt lgkmcnt(0)" ::: "memory");

    bf16x8 pf[2][2];
#pragma unroll
    for (int qg = 0; qg < 2; ++qg)
#pragma unroll
      for (int kc = 0; kc < 2; ++kc)
        pf[qg][kc] = *reinterpret_cast<const bf16x8*>(
            &Ps[w][(qg * 16 + lq) * 72 + kc * 32 + quad * 8]);

#pragma unroll
    for (int dg = 0; dg < 4; ++dg) {
      const bf16x8 vf0 = *reinterpret_cast<const bf16x8*>(
          &Vs[(((dg * 16 + lq) * 8) + (quad ^ x7)) * 8]);
      const bf16x8 vf1 = *reinterpret_cast<const bf16x8*>(
          &Vs[(((dg * 16 + lq) * 8) + ((4 + quad) ^ x7)) * 8]);
#pragma unroll
      for (int qg = 0; qg < 2; ++qg) {
        O[qg][dg] = __builtin_amdgcn_mfma_f32_16x16x32_bf16(pf[qg][0], vf0, O[qg][dg], 0, 0, 0);
        O[qg][dg] = __builtin_amdgcn_mfma_f32_16x16x32_bf16(pf[qg][1], vf1, O[qg][dg], 0, 0, 0);
      }
    }
  }

  float inv[2];
#pragma unroll
  for (int qg = 0; qg < 2; ++qg) {
    float l = lsum[qg];
    l += __shfl_xor(l, 16, 64);
    l += __shfl_xor(l, 32, 64);
    inv[qg] = 1.f / l;
  }

#pragma unroll
  for (int qg = 0; qg < 2; ++qg) {
#pragma unroll
    for (int r = 0; r < 4; ++r) {
      const float iv = __shfl(inv[qg], quad * 4 + r, 64);
      const size_t trow = (size_t)(qt * 128 + w * 32 + qg * 16 + quad * 4 + r);
      float* op = out + ((size_t)b * 2048 + trow) * 1024 + h * 64 + lq;
#pragma unroll
      for (int dg = 0; dg < 4; ++dg) op[dg * 16] = O[qg][dg][r] * iv;
    }
  }
}

extern "C" void kernel_launch(void* const* d_in, const int* in_sizes, int n_in,
                              void* d_out, int out_size, void* d_ws, size_t ws_size,
                              hipStream_t stream) {
  (void)in_sizes; (void)n_in; (void)out_size; (void)ws_size;
  const float* x = (const float*)d_in[0];
  const float* Wq = (const float*)d_in[1];
  const float* Wk = (const float*)d_in[2];
  const float* Wv = (const float*)d_in[3];
  const float* wip = (const float*)d_in[4];
  float* out = (float*)d_out;

  u16* xb = (u16*)d_ws;
  u16* wb = xb + 8388608;
  u16* qb = wb + 3145728;
  u16* kb = qb + 8388608;
  u16* vb = kb + 8388608;   // holds V^T [B][H][64][2048]

  cvt_all<<<11264, 256, 0, stream>>>(x, Wq, Wk, Wv, xb, wb);
  qkv_gemm<<<dim3(64, 8, 3), 256, 0, stream>>>(xb, wb, qb);
  palace_attn<<<dim3(64, 16, 1), 256, 0, stream>>>(qb, kb, vb, out, wip);
}